// Round 5
// baseline (323.610 us; speedup 1.0000x reference)
//
#include <hip/hip_runtime.h>
#include <stdint.h>

// Problem constants (fixed by the reference)
#define CHARS   10000
#define KPAD    10240   // K padded to multiple of 64
#define HIDDEN  1024
#define OUTPUT  100
#define OPAD    128     // padded output cols for coalesced W2T
#define BATCH   4096
#define MAXLEN  2048

typedef __bf16 bf16_t;
typedef __bf16 bf16x8 __attribute__((ext_vector_type(8)));
typedef __bf16 bf16x4 __attribute__((ext_vector_type(4)));
typedef float  f32x4  __attribute__((ext_vector_type(4)));
typedef uint32_t u32x4 __attribute__((ext_vector_type(4)));

// async global->LDS, 16B per lane; LDS dst = wave-uniform base + lane*16 (linear)
__device__ __forceinline__ void gload16(const bf16_t* g, bf16_t* l) {
    __builtin_amdgcn_global_load_lds(
        (__attribute__((address_space(1))) void*)const_cast<bf16_t*>(g),
        (__attribute__((address_space(3))) void*)l, 16, 0, 0);
}

// ---------------------------------------------------------------------------
// Fused prep:
//   blocks [0,2048)    : W1 (HIDDEN x CHARS fp32) -> W1b (HIDDEN x KPAD bf16)
//   blocks [2048,2560) : W2 (OUTPUT x HIDDEN fp32) -> W2T (HIDDEN x OPAD fp32)
//   blocks [2560,4608) : hid[b,h] = b1[h]  (split-K GEMM atomically adds on top)
// ---------------------------------------------------------------------------
__global__ void k_prep(const float* __restrict__ W1, bf16_t* __restrict__ W1b,
                       const float* __restrict__ W2, float* __restrict__ W2T,
                       const float* __restrict__ b1, float* __restrict__ hid) {
    const int bid = blockIdx.x, tid = threadIdx.x;
    if (bid < 2048) {
        const int N4 = (KPAD / 4) * HIDDEN;       // 2.62M float4-groups
        for (int i = bid * 256 + tid; i < N4; i += 2048 * 256) {
            int c4 = i % (KPAD / 4);
            int h  = i / (KPAD / 4);
            bf16x4 o;
            if (c4 * 4 < CHARS) {                 // CHARS % 4 == 0 -> clean split
                f32x4 v = *(const f32x4*)(W1 + (size_t)h * CHARS + (size_t)c4 * 4);
                o[0] = (bf16_t)v[0]; o[1] = (bf16_t)v[1];
                o[2] = (bf16_t)v[2]; o[3] = (bf16_t)v[3];
            } else {
                o[0] = o[1] = o[2] = o[3] = (bf16_t)0.0f;
            }
            *(bf16x4*)(W1b + (size_t)h * KPAD + (size_t)c4 * 4) = o;
        }
    } else if (bid < 2560) {
        int i = (bid - 2048) * 256 + tid;         // 0..131071 = HIDDEN*OPAD
        int o = i & (OPAD - 1), k = i >> 7;
        W2T[i] = (o < OUTPUT) ? W2[(size_t)o * HIDDEN + k] : 0.0f;
    } else {
        const int M4 = BATCH * HIDDEN / 4;
        for (int i = (bid - 2560) * 256 + tid; i < M4; i += 2048 * 256) {
            int h4 = i & (HIDDEN / 4 - 1);
            ((f32x4*)hid)[i] = ((const f32x4*)b1)[h4];
        }
    }
}

// ---------------------------------------------------------------------------
// Per-row histogram: one block per batch row. 40KB LDS uint32 counts.
// Counts are tiny integers -> exact in bf16. Vectorized (G13).
// ---------------------------------------------------------------------------
__global__ void k_hist(const int* __restrict__ words, bf16_t* __restrict__ hist,
                       int rowStart) {
    __shared__ uint32_t h[KPAD];              // 40 KB
    const int tid = threadIdx.x;
#pragma unroll
    for (int i = 0; i < KPAD / 4 / 256; ++i)  // 10 iters
        *(u32x4*)(h + (i * 256 + tid) * 4) = (u32x4){0u, 0u, 0u, 0u};
    __syncthreads();
    const int* w = words + (size_t)(rowStart + blockIdx.x) * MAXLEN;
#pragma unroll
    for (int i = 0; i < MAXLEN / 4 / 256; ++i) {  // 2 iters
        int4 t4 = *(const int4*)(w + (i * 256 + tid) * 4);
        atomicAdd(&h[t4.x], 1u); atomicAdd(&h[t4.y], 1u);
        atomicAdd(&h[t4.z], 1u); atomicAdd(&h[t4.w], 1u);
    }
    __syncthreads();
    bf16_t* dst = hist + (size_t)blockIdx.x * KPAD;
#pragma unroll
    for (int i = 0; i < KPAD / 8 / 256; ++i) {    // 5 iters
        int j = (i * 256 + tid) * 8;
        bf16x8 o;
#pragma unroll
        for (int q = 0; q < 8; ++q) o[q] = (bf16_t)(float)h[j + q];
        *(bf16x8*)(dst + j) = o;
    }
}

// ---------------------------------------------------------------------------
// 256x256x(BK=64) bf16 MFMA GEMM, 8-phase schedule.
//   R5: LOOK-AHEAD fragment reads + COUNTED lgkm waits (T4 applied to LDS).
//   R4 measured 1950 cy/phase vs 515 cy MFMA content (MfmaUtil 26.5%): the
//   ds_reads for phase p issued in phase p + lgkmcnt(0) exposed full LDS
//   latency serially every phase. Now each phase issues the NEXT phase's
//   reads and waits lgkmcnt(N = reads just issued), so MFMA operands are
//   always >=1 phase (~600cy) old -> wait ~0. One barrier per phase.
//   Read-issue schedule (per 8-phase iter, tiles t=buf0, t+1=buf1):
//     ph1: rd b0A1(8)  st b1A1@t+1   wait 8   MM(0,0) a0b0
//     ph2: rd b0B1(4)  st b1B1@t+1   wait 4   MM(1,0) a1b0   [vm4@entry]
//     ph3: rd none     st b0B0@t+2   wait 0   MM(0,1) a0b1
//     ph4: rd b1A0B0(12) st b0A0@t+2 wait 12  MM(1,1) a1b1   [vm4@entry]
//     ph5..8: mirror for buf1 tile.
//   RAW ledger (stage -> read-issue, vmcnt(4) at entries of ph2/4/6/8 gives
//   "all but newest 2 halves landed" at each point; every pair checked):
//     b1A1 ph1->ph5, b1B1 ph2->ph6, b0B0 ph3->ph8, b0A0 ph4->ph8,
//     b0A1 ph5->ph1', b0B1 ph6->ph2', b1B0 ph7->ph4', b1A0 ph8->ph4'. All ok.
//   WAR (stage_q vs reads in flight from q-1): all 8 pairs disjoint -> one
//   barrier per phase suffices. sched_barrier(0) after each s_barrier and
//   each waitcnt pins issue order (rule 18). Counted lgkm is exact: only
//   ds_reads occupy the lgkm queue in the loop (gload_lds counts in vmcnt).
//   Split-K over slices -> fp32 atomicAdd into b1-preinitialized hid.
// ---------------------------------------------------------------------------
__global__ void __launch_bounds__(512)
k_gemm(const bf16_t* __restrict__ A, const bf16_t* __restrict__ Bt,
       float* __restrict__ hid, int KT, int mtiles) {
    __shared__ __attribute__((aligned(16))) bf16_t As[2][2][128 * 64];  // 64 KB
    __shared__ __attribute__((aligned(16))) bf16_t Bs[2][2][128 * 64];  // 64 KB

    // chunked XCD swizzle (grid % 8 == 0): same (n,s) group contiguous per XCD
    const int nblk = gridDim.x;
    int idx = blockIdx.x;
    if ((nblk & 7) == 0) idx = (idx & 7) * (nblk >> 3) + (idx >> 3);
    const int mt = idx % mtiles;
    const int ns = idx / mtiles;
    const int m0 = mt * 256;
    const int n0 = (ns & 3) * 256;        // HIDDEN/256 == 4
    const int kbeg = (ns >> 2) * KT;      // k-slice start, in 64-wide tiles

    const int tid  = threadIdx.x;
    const int lane = tid & 63;
    const int wave = tid >> 6;            // 0..7
    const int wm64 = (wave >> 2) * 64;    // wave row within 128-row quadrant half
    const int wn32 = (wave & 3) * 32;     // wave col within 128-col quadrant half
    const int l15  = lane & 15;
    const int hi   = lane >> 4;           // k-octet selector
    const int x3   = l15 & 7;             // read-side swizzle XOR

    int arow[4], brow[2], koff[2];
#pragma unroll
    for (int fi = 0; fi < 4; ++fi) arow[fi] = (wm64 + fi * 16 + l15) * 128;
#pragma unroll
    for (int fj = 0; fj < 2; ++fj) brow[fj] = (wn32 + fj * 16 + l15) * 128;
#pragma unroll
    for (int kk = 0; kk < 2; ++kk) koff[kk] = ((((kk << 2) | hi)) ^ x3) * 16;

    // staging map: wave covers 16 rows of a 128x64 half (2 issues x 8 rows);
    // lane -> row (lane>>3), 16B chunk (lane&7)^(lane>>3)  [inverse swizzle]
    const int srow = lane >> 3;
    const int csw8 = ((lane & 7) ^ srow) * 8;
    const bf16_t* Ab = A  + (size_t)(m0 + wave * 16 + srow) * KPAD + csw8;
    const bf16_t* Bb = Bt + (size_t)(n0 + wave * 16 + srow) * KPAD + csw8;
    const int wsl = wave * 2 * 512;       // LDS element offset of this wave's slot

    f32x4 acc[2][2][4][2] = {};
    bf16x8 Afa0[2][4], Afa1[2][4], Bfa0[2][4], Bfa1[2][4];
    bf16x8 Afb0[2][2], Afb1[2][2], Bfb0[2][2], Bfb1[2][2];

#define STAGE(SB, SOP, SH, KTILE_) do {                                        \
    int kte_ = (KTILE_); if (kte_ >= KT) kte_ = 0; /* tail clamp */            \
    const size_t kc_ = (size_t)(kbeg + kte_) * 64;                             \
    const bf16_t* gb_ = (SOP) ? Bb : Ab;                                       \
    bf16_t* lb_ = ((SOP) ? &Bs[SB][SH][0] : &As[SB][SH][0]) + wsl;             \
    gload16(gb_ + (size_t)((SH) * 128)     * KPAD + kc_, lb_);                 \
    gload16(gb_ + (size_t)((SH) * 128 + 8) * KPAD + kc_, lb_ + 512);           \
} while (0)

#define LOADA(DST, PB, HALF) do {                                              \
    const char* p_ = (const char*)&As[PB][HALF][0];                            \
    _Pragma("unroll") for (int kk = 0; kk < 2; ++kk)                           \
        _Pragma("unroll") for (int fi = 0; fi < 4; ++fi)                       \
            DST[kk][fi] = *(const bf16x8*)(p_ + arow[fi] + koff[kk]);          \
} while (0)

#define LOADB(DST, PB, HALF) do {                                              \
    const char* p_ = (const char*)&Bs[PB][HALF][0];                            \
    _Pragma("unroll") for (int kk = 0; kk < 2; ++kk)                           \
        _Pragma("unroll") for (int fj = 0; fj < 2; ++fj)                       \
            DST[kk][fj] = *(const bf16x8*)(p_ + brow[fj] + koff[kk]);          \
} while (0)

// phase-entry barrier (sched_barrier keeps ds_reads/stages from hoisting over)
#define BAR() do {                                                             \
    __builtin_amdgcn_s_barrier();                                              \
    __builtin_amdgcn_sched_barrier(0);                                         \
} while (0)

// counted vmcnt drain BEFORE the barrier (cross-wave stage visibility)
#define VM4() do {                                                             \
    asm volatile("s_waitcnt vmcnt(4)" ::: "memory");                           \
} while (0)

// counted lgkm wait: all but the N just-issued ds_reads are complete
#define WAITK(N) do {                                                          \
    asm volatile("s_waitcnt lgkmcnt(" #N ")" ::: "memory");                    \
    __builtin_amdgcn_sched_barrier(0);                                         \
} while (0)

#define MMQ(QI, QJ, FA, FB) do {                                               \
    __builtin_amdgcn_s_setprio(1);                                             \
    _Pragma("unroll") for (int kk = 0; kk < 2; ++kk)                           \
        _Pragma("unroll") for (int fi = 0; fi < 4; ++fi)                       \
            _Pragma("unroll") for (int fj = 0; fj < 2; ++fj)                   \
                acc[QI][QJ][fi][fj] = __builtin_amdgcn_mfma_f32_16x16x32_bf16( \
                    FA[kk][fi], FB[kk][fj], acc[QI][QJ][fi][fj], 0, 0, 0);     \
    __builtin_amdgcn_s_setprio(0);                                             \
} while (0)

    // prologue: tile0 complete into buf0, tile1 {B0,A0} into buf1;
    // vmcnt(4) leaves only {b1B0,b1A0} in flight -> all buf0 halves landed.
    STAGE(0, 0, 0, 0);
    STAGE(0, 1, 0, 0);
    STAGE(0, 0, 1, 0);
    STAGE(0, 1, 1, 0);
    STAGE(1, 1, 0, 1);
    STAGE(1, 0, 0, 1);
    VM4();
    __builtin_amdgcn_s_barrier();
    __builtin_amdgcn_sched_barrier(0);
    LOADA(Afa0, 0, 0);                    // 12 reads for ph1's MFMA
    LOADB(Afb0, 0, 0);

    for (int kt = 0; kt < KT; kt += 2) {
        // ph1
        BAR();
        STAGE(1, 0, 1, kt + 1);           // b1A1
        LOADA(Afa1, 0, 1);                // for ph2
        WAITK(8);  MMQ(0, 0, Afa0, Afb0);
        // ph2
        VM4(); BAR();
        STAGE(1, 1, 1, kt + 1);           // b1B1
        LOADB(Afb1, 0, 1);                // for ph3
        WAITK(4);  MMQ(1, 0, Afa1, Afb0);
        // ph3
        BAR();
        STAGE(0, 1, 0, kt + 2);           // b0B0
        WAITK(0);  MMQ(0, 1, Afa0, Afb1);
        // ph4
        VM4(); BAR();
        STAGE(0, 0, 0, kt + 2);           // b0A0
        LOADA(Bfa0, 1, 0);                // for ph5
        LOADB(Bfb0, 1, 0);
        WAITK(12); MMQ(1, 1, Afa1, Afb1);
        // ph5
        BAR();
        STAGE(0, 0, 1, kt + 2);           // b0A1
        LOADA(Bfa1, 1, 1);                // for ph6
        WAITK(8);  MMQ(0, 0, Bfa0, Bfb0);
        // ph6
        VM4(); BAR();
        STAGE(0, 1, 1, kt + 2);           // b0B1
        LOADB(Bfb1, 1, 1);                // for ph7
        WAITK(4);  MMQ(1, 0, Bfa1, Bfb0);
        // ph7
        BAR();
        STAGE(1, 1, 0, kt + 3);           // b1B0
        WAITK(0);  MMQ(0, 1, Bfa0, Bfb1);
        // ph8
        VM4(); BAR();
        STAGE(1, 0, 0, kt + 3);           // b1A0
        LOADA(Afa0, 0, 0);                // for next ph1 (dead reads on last iter)
        LOADB(Afb0, 0, 0);
        WAITK(12); MMQ(1, 1, Bfa1, Bfb1);
    }
#undef MMQ
#undef WAITK
#undef VM4
#undef BAR
#undef LOADB
#undef LOADA
#undef STAGE

    // epilogue: C/D layout col=lane&15, row=(lane>>4)*4+reg  [guide §3, m89]
    const int er = hi * 4;
#pragma unroll
    for (int qi = 0; qi < 2; ++qi)
#pragma unroll
    for (int qj = 0; qj < 2; ++qj)
#pragma unroll
    for (int fi = 0; fi < 4; ++fi)
#pragma unroll
    for (int fj = 0; fj < 2; ++fj) {
        float* dst = hid + (size_t)(m0 + qi * 128 + wm64 + fi * 16 + er) * HIDDEN
                         + (n0 + qj * 128 + wn32 + fj * 16 + l15);
#pragma unroll
        for (int r = 0; r < 4; ++r)
            atomicAdd(dst + (size_t)r * HIDDEN, acc[qi][qj][fi][fj][r]);
    }
}

// ---------------------------------------------------------------------------
// out[b,o] = sum_k hid[b,k] * W2T[k,o] + b2[o]
// ---------------------------------------------------------------------------
__global__ void k_out(const float* __restrict__ hid, const float* __restrict__ W2T,
                      const float* __restrict__ b2, float* __restrict__ out) {
    const int tid = threadIdx.x;
    const int o4  = (tid & 31) * 4;       // 0,4,...,124
    const int rs  = tid >> 5;             // 0..7
    const int row = blockIdx.x * 8 + rs;
    const float* hrow = hid + (size_t)row * HIDDEN;
    f32x4 acc = {0.f, 0.f, 0.f, 0.f};
    for (int k0 = 0; k0 < HIDDEN; k0 += 4) {
        f32x4 hv = *(const f32x4*)(hrow + k0);
#pragma unroll
        for (int q = 0; q < 4; ++q) {
            f32x4 wv = *(const f32x4*)(W2T + (size_t)(k0 + q) * OPAD + o4);
            acc += hv[q] * wv;
        }
    }
    if (o4 < OUTPUT) {
        float* op = out + (size_t)row * OUTPUT + o4;
#pragma unroll
        for (int q = 0; q < 4; ++q)
            op[q] = acc[q] + b2[o4 + q];
    }
}

// ---------------------------------------------------------------------------
// split-K: largest S with grid = mtiles*4*S <= 256 (1 block/CU at 128KB LDS);
// all candidates divide 160 with even quotient (template needs even KT).
// ---------------------------------------------------------------------------
static inline int pick_S(int mtiles) {
    const int cands[10] = {80, 40, 20, 16, 10, 8, 5, 4, 2, 1};
    for (int i = 0; i < 10; ++i)
        if (mtiles * 4 * cands[i] <= 256) return cands[i];
    return 1;
}

extern "C" void kernel_launch(void* const* d_in, const int* in_sizes, int n_in,
                              void* d_out, int out_size, void* d_ws, size_t ws_size,
                              hipStream_t stream) {
    (void)in_sizes; (void)n_in; (void)out_size;
    const int*   words = (const int*)d_in[0];
    const float* W1    = (const float*)d_in[1];
    const float* b1    = (const float*)d_in[2];
    const float* W2    = (const float*)d_in[3];
    const float* b2    = (const float*)d_in[4];
    float* out = (float*)d_out;

    // workspace layout
    char* ws = (char*)d_ws;
    size_t off = 0;
    bf16_t* W1b  = (bf16_t*)(ws + off); off += (size_t)HIDDEN * KPAD * sizeof(bf16_t); // 21.0 MB
    float*  hid  = (float*) (ws + off); off += (size_t)BATCH * HIDDEN * sizeof(float); // 16.8 MB
    float*  W2T  = (float*) (ws + off); off += (size_t)HIDDEN * OPAD * sizeof(float);  // 0.5 MB
    bf16_t* histC = (bf16_t*)(ws + off);
    size_t rem = (ws_size > off) ? (ws_size - off) : 0;
    int chunkRows = (int)(rem / ((size_t)KPAD * sizeof(bf16_t)));
    chunkRows = (chunkRows / 256) * 256;
    if (chunkRows > BATCH) chunkRows = BATCH;
    if (chunkRows < 256)   chunkRows = 256;

    k_prep<<<dim3(4608), dim3(256), 0, stream>>>(W1, W1b, W2, W2T, b1, hid);

    for (int r0 = 0; r0 < BATCH; r0 += chunkRows) {
        int rows = BATCH - r0;
        if (rows > chunkRows) rows = chunkRows;
        k_hist<<<dim3(rows), dim3(256), 0, stream>>>(words, histC, r0);
        int mtiles = rows / 256;
        int S = pick_S(mtiles);
        int KT = (KPAD / 64) / S;
        k_gemm<<<dim3(mtiles * 4 * S), dim3(512), 0, stream>>>(
            histC, W1b, hid + (size_t)r0 * HIDDEN, KT, mtiles);
    }

    k_out<<<dim3(BATCH / 8), dim3(256), 0, stream>>>(hid, W2T, b2, out);
}